// Round 6
// baseline (445.167 us; speedup 1.0000x reference)
//
#include <hip/hip_runtime.h>

// LTFGW semi-relaxed FGW — round 6: kill the AGPR spills.
// Round-5 finding: VGPR_Count=36 with ~60 live floats -> compiler spilled
// the per-thread arrays through AGPRs (occupancy-targeted default budget),
// inflating VALU ~2.3x (740 vs ~320 instr/wave-iter). Fixes:
//   1. __launch_bounds__(1024, 4): 4 waves/EU floor -> 128-VGPR budget.
//   2. __builtin_amdgcn_exp2f (raw v_exp_f32; libm exp2f was the SLOW path)
//      + __builtin_amdgcn_rcpf for the softmax normalizer.
//   3. gcost: GV=16 nodes/block (640 thr) -> halves F2-staging per node.
// Structure otherwise = round 5 (wave-per-template, DPP q, dual-atomicOr
// masks, scalar-C2 y2 matvec, exp2-domain logits).

#define NN    6000
#define DEG   16
#define MM    17
#define NTPL  16
#define MT    10
#define NF    128
#define NITER 10
#define KPB   16
#define NPB   3
#define BS    1024
#define RS    12            // padded T row stride (floats)
#define LOG2E 1.44269504088896340736f

template<int C>
__device__ __forceinline__ float ror_add(float v) {
    int s = __builtin_amdgcn_update_dpp(0, __float_as_int(v), C, 0xf, 0xf, true);
    return v + __int_as_float(s);
}

__device__ __forceinline__ float fexp2(float x) { return __builtin_amdgcn_exp2f(x); }
__device__ __forceinline__ float frcp(float x)  { return __builtin_amdgcn_rcpf(x); }

// ---------------- gcost: G[v, k*10+t] = mcoefl*(||F2[kt]||^2 - 2 x[v].F2[kt])
#define GV 16
__global__ __launch_bounds__(640, 2) void gcost_kernel(
    const float* __restrict__ x, const float* __restrict__ F2g,
    const float* __restrict__ alpha0, float* __restrict__ G)
{
    const int tx  = threadIdx.x;          // 0..39 : kt quad
    const int vs  = threadIdx.y;          // 0..15 : node in block
    const int tid = vs * 40 + tx;
    const int v0  = blockIdx.x * GV;

    __shared__ __align__(16) float s_x[GV][NF];        // 8 KB
    __shared__ __align__(16) float s_f2t[16][164];     // 10.5 KB

    // stage x rows (coalesced float4)
    {
        const float4* xg  = reinterpret_cast<const float4*>(x);
        float4*       sx4 = reinterpret_cast<float4*>(&s_x[0][0]);
        for (int i = tid; i < GV * 32; i += 640) {
            int row = i >> 5, c = i & 31;
            sx4[i] = xg[(size_t)(v0 + row) * 32 + c];
        }
    }

    float4 acc = make_float4(0.f, 0.f, 0.f, 0.f);
    float4 sq  = make_float4(0.f, 0.f, 0.f, 0.f);

    for (int fc = 0; fc < 8; fc++) {
        __syncthreads();
        // stage F2[:, fc*16 .. fc*16+15] transposed: s_f2t[j][kt]
        for (int i = tid; i < 160 * 16; i += 640) {
            int kt = i >> 4, j = i & 15;
            s_f2t[j][kt] = F2g[(size_t)kt * NF + fc * 16 + j];
        }
        __syncthreads();

        const float4* sxr = reinterpret_cast<const float4*>(&s_x[vs][0]);
        #pragma unroll
        for (int u = 0; u < 4; u++) {
            float4 xa = sxr[fc * 4 + u];
            #pragma unroll
            for (int jj = 0; jj < 4; jj++) {
                float xs = (&xa.x)[jj];
                const float4* br = reinterpret_cast<const float4*>(&s_f2t[u * 4 + jj][0]);
                float4 b = br[tx];
                acc.x = fmaf(xs, b.x, acc.x); acc.y = fmaf(xs, b.y, acc.y);
                acc.z = fmaf(xs, b.z, acc.z); acc.w = fmaf(xs, b.w, acc.w);
                sq.x  = fmaf(b.x, b.x, sq.x); sq.y  = fmaf(b.y, b.y, sq.y);
                sq.z  = fmaf(b.z, b.z, sq.z); sq.w  = fmaf(b.w, b.w, sq.w);
            }
        }
    }

    const float alpha  = 1.f / (1.f + __expf(-alpha0[0]));
    const float mcoefl = (1.f - alpha) * 10.f * LOG2E;
    float4 g;
    g.x = mcoefl * (sq.x - 2.f * acc.x);
    g.y = mcoefl * (sq.y - 2.f * acc.y);
    g.z = mcoefl * (sq.z - 2.f * acc.z);
    g.w = mcoefl * (sq.w - 2.f * acc.w);
    float4* Gp = reinterpret_cast<float4*>(G + (size_t)(v0 + vs) * (NTPL * MT));
    Gp[tx] = g;
}

// ---------------- main kernel
__global__ __launch_bounds__(BS, 4) void srfgw_kernel(
    const float* __restrict__ x,
    const int*   __restrict__ dst,
    const float* __restrict__ C2g,
    const float* __restrict__ F2g,
    const float* __restrict__ alpha0,
    const float* __restrict__ G,
    int useG,
    float*       __restrict__ out)
{
    const int nb  = blockIdx.x * NPB;
    const int tid = threadIdx.x;

    __shared__ __align__(16) float s_T[KPB][NPB][MM][RS];     // 39168 B
    __shared__ __align__(16) float s_C2sq[KPB][MT][RS];       // 7680 B (pre-scaled gcoef*log2e)
    __shared__ __align__(16) float s_q[KPB][NPB][RS];         // 2304 B
    __shared__ __align__(16) float s_cc[KPB][NPB][RS];        // 2304 B
    __shared__ __align__(16) int   s_adj[NPB * MM][DEG];      // 3264 B
    __shared__ int      s_nbr[NPB][MM];
    __shared__ unsigned s_mask[NPB][MM];

    const float aval  = alpha0[0];
    const float alpha = 1.f / (1.f + __expf(-aval));
    const float gcoef = 2.f * alpha * 10.f;
    const float tgl   = 2.f * gcoef * LOG2E;       // y2 scale, log2 domain
    const float gl2   = gcoef * LOG2E;             // C2sq prescale

    if (tid < NPB * MM) {
        int node = tid / MM, a0 = tid - node * MM;
        s_nbr[node][a0]  = (a0 == 0) ? (nb + node) : dst[(size_t)(nb + node) * DEG + a0 - 1];
        s_mask[node][a0] = 0u;
    }
    __syncthreads();

    // stage adjacency rows of all 51 neighbors (816 <= BS)
    if (tid < NPB * MM * DEG) {
        int r = tid >> 4, j = tid & 15;
        int node = r / MM, a0 = r - node * MM;
        s_adj[r][j] = dst[(size_t)s_nbr[node][a0] * DEG + j];
    }
    // C2^2 * gcoef*log2e — STRIDED (1600 > BS)
    for (int i = tid; i < KPB * MT * MT; i += BS) {
        int kk = i / (MT * MT), rr = i - kk * (MT * MT);
        int rs = rr / MT, rt = rr - rs * MT;
        float v = C2g[i];
        s_C2sq[kk][rs][rt] = gl2 * v * v;
    }
    __syncthreads();

    // masks: directed edge nbr[pa]->nbr[pb]? set both bits (symmetrize). 867<=BS
    if (tid < NPB * MM * MM) {
        int node = tid / (MM * MM), rr = tid - node * (MM * MM);
        int pa = rr / MM, pb = rr - pa * MM;
        int vtgt = s_nbr[node][pb];
        const int* ar = s_adj[node * MM + pa];
        bool e = false;
        #pragma unroll
        for (int j = 0; j < DEG; j++) e = e | (ar[j] == vtgt);
        if (e) {
            atomicOr(&s_mask[node][pa], 1u << pb);
            atomicOr(&s_mask[node][pb], 1u << pa);
        }
    }
    __syncthreads();

    // ---- lane mapping: wave kw owns template kw; 3 groups/wave ----
    const int  kw    = tid >> 6;           // 0..15 == template
    const int  ln    = tid & 63;
    const bool isR16 = (ln >= 48) && (ln < 51);
    const bool valid = (ln < 51);
    int g = isR16 ? (ln - 48) : (ln >> 4);
    if (g >= NPB) g = 0;
    const int a = isR16 ? 16 : (ln & 15);

    const int k_u = __builtin_amdgcn_readfirstlane(kw);
    const float* __restrict__ c2p = C2g + (size_t)k_u * MT * MT;

    const int vv = s_nbr[g][a];

    // ---- Mc (log2-scaled) from G, or inline fallback ----
    float Mc[MT];
    if (useG) {
        const float2* gp = reinterpret_cast<const float2*>(G + (size_t)vv * (NTPL * MT) + k_u * MT);
        #pragma unroll
        for (int j = 0; j < 5; j++) {
            float2 w = gp[j];
            Mc[2 * j] = w.x; Mc[2 * j + 1] = w.y;
        }
    } else {
        float dot[MT], sq2[MT];
        #pragma unroll
        for (int t = 0; t < MT; t++) { dot[t] = 0.f; sq2[t] = 0.f; }
        const float4* xr = reinterpret_cast<const float4*>(x + (size_t)vv * NF);
        const float4* fr = reinterpret_cast<const float4*>(F2g + (size_t)k_u * MT * NF);
        for (int f = 0; f < NF / 4; f++) {
            float4 xa = xr[f];
            #pragma unroll
            for (int t = 0; t < MT; t++) {
                float4 b = fr[t * (NF / 4) + f];
                dot[t] += xa.x * b.x + xa.y * b.y + xa.z * b.z + xa.w * b.w;
                sq2[t] += b.x * b.x + b.y * b.y + b.z * b.z + b.w * b.w;
            }
        }
        const float mcoefl = (1.f - alpha) * 10.f * LOG2E;
        #pragma unroll
        for (int t = 0; t < MT; t++) Mc[t] = mcoefl * (sq2[t] - 2.f * dot[t]);
    }

    // ---- sparse Y1 setup ----
    unsigned mask = valid ? s_mask[g][a] : 0u;
    const int  pcnt = __popc(mask);
    const bool cmpl = pcnt > 8;
    unsigned   lmask = cmpl ? (~mask & 0x1FFFFu) : mask;
    if (!valid) lmask = 0u;
    const float sgn = cmpl ? -1.f : 1.f;
    const float P   = 1.f / 17.f;

    float lt[MT];
    #pragma unroll
    for (int t = 0; t < MT; t++) lt[t] = 0.f;

    float4* Trow = reinterpret_cast<float4*>(&s_T[kw][g][a][0]);
    float q[MT];

    for (int it = 0; it <= NITER; it++) {
        // thread-local softmax (log2 domain, native v_exp_f32 + v_rcp_f32)
        float mx = lt[0];
        #pragma unroll
        for (int t = 1; t < MT; t++) mx = fmaxf(mx, lt[t]);
        float e[MT], ss = 0.f;
        #pragma unroll
        for (int t = 0; t < MT; t++) { e[t] = fexp2(lt[t] - mx); ss += e[t]; }
        float sc = P * frcp(ss);
        #pragma unroll
        for (int t = 0; t < MT; t++) e[t] *= sc;

        __builtin_amdgcn_wave_barrier();
        if (valid) {
            Trow[0] = make_float4(e[0], e[1], e[2], e[3]);
            Trow[1] = make_float4(e[4], e[5], e[6], e[7]);
            reinterpret_cast<float2*>(Trow)[4] = make_float2(e[8], e[9]);
        }
        __builtin_amdgcn_wave_barrier();

        // q via DPP rotate-reduce over 16-lane row
        #pragma unroll
        for (int t = 0; t < MT; t++) {
            float s = e[t];
            s = ror_add<0x121>(s);
            s = ror_add<0x122>(s);
            s = ror_add<0x124>(s);
            s = ror_add<0x128>(s);
            q[t] = s;
        }
        if (valid && a < 16) {   // add row 16 from LDS
            const float4* r16 = reinterpret_cast<const float4*>(&s_T[kw][g][16][0]);
            float4 ra = r16[0], rb = r16[1];
            float2 rc = reinterpret_cast<const float2*>(r16)[4];
            q[0] += ra.x; q[1] += ra.y; q[2] += ra.z; q[3] += ra.w;
            q[4] += rb.x; q[5] += rb.y; q[6] += rb.z; q[7] += rb.w;
            q[8] += rc.x; q[9] += rc.y;
        }
        if (valid && a == 0) {
            float2* qp = reinterpret_cast<float2*>(&s_q[kw][g][0]);
            #pragma unroll
            for (int j = 0; j < 5; j++) qp[j] = make_float2(q[2 * j], q[2 * j + 1]);
        }
        __builtin_amdgcn_wave_barrier();
        if (isR16) {
            const float2* qp = reinterpret_cast<const float2*>(&s_q[kw][g][0]);
            #pragma unroll
            for (int j = 0; j < 5; j++) {
                float2 w = qp[j];
                q[2 * j] = w.x; q[2 * j + 1] = w.y;
            }
        }
        if (it == NITER) break;

        // cooperative cc[s] (C2sq pre-scaled by gcoef*log2e)
        if (valid && a < MT) {
            const float4* cr = reinterpret_cast<const float4*>(&s_C2sq[kw][a][0]);
            float4 ca = cr[0], cb = cr[1];
            float2 c2 = reinterpret_cast<const float2*>(cr)[4];
            float cc = q[0] * ca.x + q[1] * ca.y + q[2] * ca.z + q[3] * ca.w
                     + q[4] * cb.x + q[5] * cb.y + q[6] * cb.z + q[7] * cb.w
                     + q[8] * c2.x + q[9] * c2.y;
            s_cc[kw][g][a] = cc;
        }
        __builtin_amdgcn_wave_barrier();
        float ccr[MT];
        {
            const float4* cp = reinterpret_cast<const float4*>(&s_cc[kw][g][0]);
            float4 ca = cp[0], cb = cp[1];
            float2 c2 = reinterpret_cast<const float2*>(cp)[4];
            ccr[0] = ca.x; ccr[1] = ca.y; ccr[2] = ca.z; ccr[3] = ca.w;
            ccr[4] = cb.x; ccr[5] = cb.y; ccr[6] = cb.z; ccr[7] = cb.w;
            ccr[8] = c2.x; ccr[9] = c2.y;
        }

        // Y1 via bitmask (complement trick)
        float y1[MT];
        #pragma unroll
        for (int t = 0; t < MT; t++) y1[t] = cmpl ? q[t] : 0.f;
        unsigned mm = lmask;
        while (mm) {
            int b = __ffs(mm) - 1;
            mm &= mm - 1;
            const float4* rb4 = reinterpret_cast<const float4*>(&s_T[kw][g][b][0]);
            float4 ra = rb4[0], rb = rb4[1];
            float2 rc = reinterpret_cast<const float2*>(rb4)[4];
            y1[0] += sgn * ra.x; y1[1] += sgn * ra.y; y1[2] += sgn * ra.z; y1[3] += sgn * ra.w;
            y1[4] += sgn * rb.x; y1[5] += sgn * rb.y; y1[6] += sgn * rb.z; y1[7] += sgn * rb.w;
            y1[8] += sgn * rc.x; y1[9] += sgn * rc.y;
        }

        // y2 matvec (wave-uniform scalar C2) + log2-domain update
        #pragma unroll
        for (int s = 0; s < MT; s++) {
            float y2 = 0.f;
            #pragma unroll
            for (int t = 0; t < MT; t++) y2 = fmaf(y1[t], c2p[s * MT + t], y2);
            lt[s] += tgl * y2 - ccr[s] - Mc[s];
        }
    }

    if (valid && a < MT)
        out[(size_t)(nb + g) * (NTPL * MT) + k_u * MT + a] = s_q[kw][g][a];
}

extern "C" void kernel_launch(void* const* d_in, const int* in_sizes, int n_in,
                              void* d_out, int out_size, void* d_ws, size_t ws_size,
                              hipStream_t stream) {
    const float* x      = (const float*)d_in[0];
    const int*   eidx   = (const int*)d_in[1];
    const float* tmpl   = (const float*)d_in[2];
    const float* tmplf  = (const float*)d_in[3];
    const float* alpha0 = (const float*)d_in[4];
    float*       outp   = (float*)d_out;

    const int* dst = eidx + NN * DEG;
    float* G = (float*)d_ws;
    const size_t gbytes = (size_t)NN * NTPL * MT * sizeof(float);
    int useG = (ws_size >= gbytes) ? 1 : 0;

    if (useG)
        gcost_kernel<<<dim3(NN / GV), dim3(40, GV), 0, stream>>>(x, tmplf, alpha0, G);

    srfgw_kernel<<<dim3(NN / NPB), dim3(BS), 0, stream>>>(
        x, dst, tmpl, tmplf, alpha0, G, useG, outp);
}

// Round 8
// 326.183 us; speedup vs baseline: 1.3648x; 1.3648x over previous
//
#include <hip/hip_runtime.h>

// LTFGW semi-relaxed FGW — round 8 (= round 7 with a compilable q-bridge).
// Round-7 compile fail: __builtin_amdgcn_writelane doesn't exist in this
// clang. Replacement: pull-style bridge — 3x v_readlane (lanes 0/16/32 ->
// wave-uniform SGPRs) + per-lane cndmask select on lanes 48/49/50. Pure
// full-rate VALU; still removes the 10-DS-instr q LDS glue per iteration.
// gcost: VERBATIM round-5 config (GV=8, 320 thr) — GV=16 regressed 4x.
// srfgw structure: wave-per-template, DPP q-reduce, native exp2/rcp,
// dual-atomicOr masks, scalar-C2 y2 matvec, log2-domain logits.

#define NN    6000
#define DEG   16
#define MM    17
#define NTPL  16
#define MT    10
#define NF    128
#define NITER 10
#define KPB   16
#define NPB   3
#define BS    1024
#define RS    12            // padded T row stride (floats)
#define LOG2E 1.44269504088896340736f

template<int C>
__device__ __forceinline__ float ror_add(float v) {
    int s = __builtin_amdgcn_update_dpp(0, __float_as_int(v), C, 0xf, 0xf, true);
    return v + __int_as_float(s);
}

__device__ __forceinline__ float fexp2(float x) { return __builtin_amdgcn_exp2f(x); }
__device__ __forceinline__ float frcp(float x)  { return __builtin_amdgcn_rcpf(x); }

// ---------------- gcost (round-5 verbatim): G[v,kt] = mcoefl*(||F2||^2 - 2 x.F2)
#define GV 8
__global__ __launch_bounds__(320) void gcost_kernel(
    const float* __restrict__ x, const float* __restrict__ F2g,
    const float* __restrict__ alpha0, float* __restrict__ G)
{
    const int tx  = threadIdx.x;          // 0..39 : kt quad
    const int vs  = threadIdx.y;          // 0..7  : node in block
    const int tid = vs * 40 + tx;
    const int v0  = blockIdx.x * GV;

    __shared__ __align__(16) float s_x[GV][NF];        // 4 KB
    __shared__ __align__(16) float s_f2t[16][164];     // 10.5 KB

    {
        const float4* xg  = reinterpret_cast<const float4*>(x);
        float4*       sx4 = reinterpret_cast<float4*>(&s_x[0][0]);
        for (int i = tid; i < GV * 32; i += 320) {
            int row = i >> 5, c = i & 31;
            sx4[i] = xg[(size_t)(v0 + row) * 32 + c];
        }
    }

    float4 acc = make_float4(0.f, 0.f, 0.f, 0.f);
    float4 sq  = make_float4(0.f, 0.f, 0.f, 0.f);

    for (int fc = 0; fc < 8; fc++) {
        __syncthreads();
        for (int i = tid; i < 160 * 16; i += 320) {
            int kt = i >> 4, j = i & 15;
            s_f2t[j][kt] = F2g[(size_t)kt * NF + fc * 16 + j];
        }
        __syncthreads();

        const float4* sxr = reinterpret_cast<const float4*>(&s_x[vs][0]);
        #pragma unroll
        for (int u = 0; u < 4; u++) {
            float4 xa = sxr[fc * 4 + u];
            #pragma unroll
            for (int jj = 0; jj < 4; jj++) {
                float xs = (&xa.x)[jj];
                const float4* br = reinterpret_cast<const float4*>(&s_f2t[u * 4 + jj][0]);
                float4 b = br[tx];
                acc.x = fmaf(xs, b.x, acc.x); acc.y = fmaf(xs, b.y, acc.y);
                acc.z = fmaf(xs, b.z, acc.z); acc.w = fmaf(xs, b.w, acc.w);
                sq.x  = fmaf(b.x, b.x, sq.x); sq.y  = fmaf(b.y, b.y, sq.y);
                sq.z  = fmaf(b.z, b.z, sq.z); sq.w  = fmaf(b.w, b.w, sq.w);
            }
        }
    }

    const float alpha  = 1.f / (1.f + __expf(-alpha0[0]));
    const float mcoefl = (1.f - alpha) * 10.f * LOG2E;
    float4 g;
    g.x = mcoefl * (sq.x - 2.f * acc.x);
    g.y = mcoefl * (sq.y - 2.f * acc.y);
    g.z = mcoefl * (sq.z - 2.f * acc.z);
    g.w = mcoefl * (sq.w - 2.f * acc.w);
    float4* Gp = reinterpret_cast<float4*>(G + (size_t)(v0 + vs) * (NTPL * MT));
    Gp[tx] = g;
}

// ---------------- main kernel
__global__ __launch_bounds__(BS, 4) void srfgw_kernel(
    const float* __restrict__ x,
    const int*   __restrict__ dst,
    const float* __restrict__ C2g,
    const float* __restrict__ F2g,
    const float* __restrict__ alpha0,
    const float* __restrict__ G,
    int useG,
    float*       __restrict__ out)
{
    const int nb  = blockIdx.x * NPB;
    const int tid = threadIdx.x;

    __shared__ __align__(16) float s_T[KPB][NPB][MM][RS];     // 39168 B
    __shared__ __align__(16) float s_C2sq[KPB][MT][RS];       // 7680 B
    __shared__ __align__(16) float s_q[KPB][NPB][RS];         // 2304 B (output bounce only)
    __shared__ __align__(16) float s_cc[KPB][NPB][RS];        // 2304 B
    __shared__ __align__(16) int   s_adj[NPB * MM][DEG];      // 3264 B
    __shared__ int      s_nbr[NPB][MM];
    __shared__ unsigned s_mask[NPB][MM];

    const float aval  = alpha0[0];
    const float alpha = 1.f / (1.f + __expf(-aval));
    const float gcoef = 2.f * alpha * 10.f;
    const float tgl   = 2.f * gcoef * LOG2E;
    const float gl2   = gcoef * LOG2E;

    if (tid < NPB * MM) {
        int node = tid / MM, a0 = tid - node * MM;
        s_nbr[node][a0]  = (a0 == 0) ? (nb + node) : dst[(size_t)(nb + node) * DEG + a0 - 1];
        s_mask[node][a0] = 0u;
    }
    __syncthreads();

    if (tid < NPB * MM * DEG) {
        int r = tid >> 4, j = tid & 15;
        int node = r / MM, a0 = r - node * MM;
        s_adj[r][j] = dst[(size_t)s_nbr[node][a0] * DEG + j];
    }
    for (int i = tid; i < KPB * MT * MT; i += BS) {   // strided: 1600 > BS
        int kk = i / (MT * MT), rr = i - kk * (MT * MT);
        int rs = rr / MT, rt = rr - rs * MT;
        float v = C2g[i];
        s_C2sq[kk][rs][rt] = gl2 * v * v;
    }
    __syncthreads();

    if (tid < NPB * MM * MM) {
        int node = tid / (MM * MM), rr = tid - node * (MM * MM);
        int pa = rr / MM, pb = rr - pa * MM;
        int vtgt = s_nbr[node][pb];
        const int* ar = s_adj[node * MM + pa];
        bool e = false;
        #pragma unroll
        for (int j = 0; j < DEG; j++) e = e | (ar[j] == vtgt);
        if (e) {
            atomicOr(&s_mask[node][pa], 1u << pb);
            atomicOr(&s_mask[node][pb], 1u << pa);
        }
    }
    __syncthreads();

    // ---- lane mapping: wave kw owns template kw; 3 groups/wave ----
    const int  kw    = tid >> 6;
    const int  ln    = tid & 63;
    const bool isR16 = (ln >= 48) && (ln < 51);
    const bool valid = (ln < 51);
    int g = isR16 ? (ln - 48) : (ln >> 4);
    if (g >= NPB) g = 0;
    const int a = isR16 ? 16 : (ln & 15);

    const int k_u = __builtin_amdgcn_readfirstlane(kw);
    const float* __restrict__ c2p = C2g + (size_t)k_u * MT * MT;

    const int vv = s_nbr[g][a];

    float Mc[MT];
    if (useG) {
        const float2* gp = reinterpret_cast<const float2*>(G + (size_t)vv * (NTPL * MT) + k_u * MT);
        #pragma unroll
        for (int j = 0; j < 5; j++) {
            float2 w = gp[j];
            Mc[2 * j] = w.x; Mc[2 * j + 1] = w.y;
        }
    } else {
        float dot[MT], sq2[MT];
        #pragma unroll
        for (int t = 0; t < MT; t++) { dot[t] = 0.f; sq2[t] = 0.f; }
        const float4* xr = reinterpret_cast<const float4*>(x + (size_t)vv * NF);
        const float4* fr = reinterpret_cast<const float4*>(F2g + (size_t)k_u * MT * NF);
        for (int f = 0; f < NF / 4; f++) {
            float4 xa = xr[f];
            #pragma unroll
            for (int t = 0; t < MT; t++) {
                float4 b = fr[t * (NF / 4) + f];
                dot[t] += xa.x * b.x + xa.y * b.y + xa.z * b.z + xa.w * b.w;
                sq2[t] += b.x * b.x + b.y * b.y + b.z * b.z + b.w * b.w;
            }
        }
        const float mcoefl = (1.f - alpha) * 10.f * LOG2E;
        #pragma unroll
        for (int t = 0; t < MT; t++) Mc[t] = mcoefl * (sq2[t] - 2.f * dot[t]);
    }

    unsigned mask = valid ? s_mask[g][a] : 0u;
    const int  pcnt = __popc(mask);
    const bool cmpl = pcnt > 8;
    unsigned   lmask = cmpl ? (~mask & 0x1FFFFu) : mask;
    if (!valid) lmask = 0u;
    const float sgn = cmpl ? -1.f : 1.f;
    const float P   = 1.f / 17.f;

    float lt[MT];
    #pragma unroll
    for (int t = 0; t < MT; t++) lt[t] = 0.f;

    float4* Trow = reinterpret_cast<float4*>(&s_T[kw][g][a][0]);
    float q[MT];

    for (int it = 0; it <= NITER; it++) {
        // thread-local softmax (log2 domain, native v_exp_f32 + v_rcp_f32)
        float mx = lt[0];
        #pragma unroll
        for (int t = 1; t < MT; t++) mx = fmaxf(mx, lt[t]);
        float e[MT], ss = 0.f;
        #pragma unroll
        for (int t = 0; t < MT; t++) { e[t] = fexp2(lt[t] - mx); ss += e[t]; }
        float sc = P * frcp(ss);
        #pragma unroll
        for (int t = 0; t < MT; t++) e[t] *= sc;

        __builtin_amdgcn_wave_barrier();
        if (valid) {
            Trow[0] = make_float4(e[0], e[1], e[2], e[3]);
            Trow[1] = make_float4(e[4], e[5], e[6], e[7]);
            reinterpret_cast<float2*>(Trow)[4] = make_float2(e[8], e[9]);
        }
        __builtin_amdgcn_wave_barrier();

        // q via DPP rotate-reduce over 16-lane row (all 16 lanes get the sum)
        #pragma unroll
        for (int t = 0; t < MT; t++) {
            float s = e[t];
            s = ror_add<0x121>(s);
            s = ror_add<0x122>(s);
            s = ror_add<0x124>(s);
            s = ror_add<0x128>(s);
            q[t] = s;
        }
        if (valid && a < 16) {   // add row 16 from LDS
            const float4* r16 = reinterpret_cast<const float4*>(&s_T[kw][g][16][0]);
            float4 ra = r16[0], rb = r16[1];
            float2 rc = reinterpret_cast<const float2*>(r16)[4];
            q[0] += ra.x; q[1] += ra.y; q[2] += ra.z; q[3] += ra.w;
            q[4] += rb.x; q[5] += rb.y; q[6] += rb.z; q[7] += rb.w;
            q[8] += rc.x; q[9] += rc.y;
        }
        // bridge q to row-16 lanes (48/49/50): pull-style — v_readlane of the
        // group leaders into wave-uniform SGPRs + cndmask select per lane.
        // Pure full-rate VALU; lane-mask compares are loop-invariant.
        #pragma unroll
        for (int t = 0; t < MT; t++) {
            int qi = __float_as_int(q[t]);
            int s0 = __builtin_amdgcn_readlane(qi, 0);
            int s1 = __builtin_amdgcn_readlane(qi, 16);
            int s2 = __builtin_amdgcn_readlane(qi, 32);
            int sel = (ln == 48) ? s0 : (ln == 49) ? s1 : (ln == 50) ? s2 : qi;
            q[t] = __int_as_float(sel);
        }
        if (it == NITER) break;

        // cooperative cc[s] (C2sq pre-scaled by gcoef*log2e)
        if (valid && a < MT) {
            const float4* cr = reinterpret_cast<const float4*>(&s_C2sq[kw][a][0]);
            float4 ca = cr[0], cb = cr[1];
            float2 c2 = reinterpret_cast<const float2*>(cr)[4];
            float cc = q[0] * ca.x + q[1] * ca.y + q[2] * ca.z + q[3] * ca.w
                     + q[4] * cb.x + q[5] * cb.y + q[6] * cb.z + q[7] * cb.w
                     + q[8] * c2.x + q[9] * c2.y;
            s_cc[kw][g][a] = cc;
        }
        __builtin_amdgcn_wave_barrier();
        float ccr[MT];
        {
            const float4* cp = reinterpret_cast<const float4*>(&s_cc[kw][g][0]);
            float4 ca = cp[0], cb = cp[1];
            float2 c2 = reinterpret_cast<const float2*>(cp)[4];
            ccr[0] = ca.x; ccr[1] = ca.y; ccr[2] = ca.z; ccr[3] = ca.w;
            ccr[4] = cb.x; ccr[5] = cb.y; ccr[6] = cb.z; ccr[7] = cb.w;
            ccr[8] = c2.x; ccr[9] = c2.y;
        }

        // Y1 via bitmask (complement trick)
        float y1[MT];
        #pragma unroll
        for (int t = 0; t < MT; t++) y1[t] = cmpl ? q[t] : 0.f;
        unsigned mm = lmask;
        while (mm) {
            int b = __ffs(mm) - 1;
            mm &= mm - 1;
            const float4* rb4 = reinterpret_cast<const float4*>(&s_T[kw][g][b][0]);
            float4 ra = rb4[0], rb = rb4[1];
            float2 rc = reinterpret_cast<const float2*>(rb4)[4];
            y1[0] += sgn * ra.x; y1[1] += sgn * ra.y; y1[2] += sgn * ra.z; y1[3] += sgn * ra.w;
            y1[4] += sgn * rb.x; y1[5] += sgn * rb.y; y1[6] += sgn * rb.z; y1[7] += sgn * rb.w;
            y1[8] += sgn * rc.x; y1[9] += sgn * rc.y;
        }

        // y2 matvec (wave-uniform scalar C2) + log2-domain update
        #pragma unroll
        for (int s = 0; s < MT; s++) {
            float y2 = 0.f;
            #pragma unroll
            for (int t = 0; t < MT; t++) y2 = fmaf(y1[t], c2p[s * MT + t], y2);
            lt[s] += tgl * y2 - ccr[s] - Mc[s];
        }
    }

    // output bounce via s_q (once)
    if (valid && a == 0) {
        float2* qp = reinterpret_cast<float2*>(&s_q[kw][g][0]);
        #pragma unroll
        for (int j = 0; j < 5; j++) qp[j] = make_float2(q[2 * j], q[2 * j + 1]);
    }
    __builtin_amdgcn_wave_barrier();
    if (valid && a < MT)
        out[(size_t)(nb + g) * (NTPL * MT) + k_u * MT + a] = s_q[kw][g][a];
}

extern "C" void kernel_launch(void* const* d_in, const int* in_sizes, int n_in,
                              void* d_out, int out_size, void* d_ws, size_t ws_size,
                              hipStream_t stream) {
    const float* x      = (const float*)d_in[0];
    const int*   eidx   = (const int*)d_in[1];
    const float* tmpl   = (const float*)d_in[2];
    const float* tmplf  = (const float*)d_in[3];
    const float* alpha0 = (const float*)d_in[4];
    float*       outp   = (float*)d_out;

    const int* dst = eidx + NN * DEG;
    float* G = (float*)d_ws;
    const size_t gbytes = (size_t)NN * NTPL * MT * sizeof(float);
    int useG = (ws_size >= gbytes) ? 1 : 0;

    if (useG)
        gcost_kernel<<<dim3(NN / GV), dim3(40, GV), 0, stream>>>(x, tmplf, alpha0, G);

    srfgw_kernel<<<dim3(NN / NPB), dim3(BS), 0, stream>>>(
        x, dst, tmpl, tmplf, alpha0, G, useG, outp);
}

// Round 9
// 246.387 us; speedup vs baseline: 1.8068x; 1.3239x over previous
//
#include <hip/hip_runtime.h>

// LTFGW semi-relaxed FGW — round 9.
// Round-8 lesson: VALUBusy ~85% -> VALU is the binding pipe; the readlane
//   bridge (DS->VALU trade) regressed 205->273 us. REVERTED to round-6's
//   LDS q-glue (DS overlaps VALU issue).
// New: iteration-0 folded analytically (exact): lt=0 -> T uniform ->
//   lt_1[s] = pcnt*A_k[s] - B_k[s] - Mc[s], A=(tgl/170)*rowsum(C2),
//   B=0.1*gl2*rowsum(C2^2), precomputed by 160 preamble threads. Loop runs
//   10 softmax + 9 grad phases instead of 11+10 (~9.5% VALU cut).
// gcost: round-5 verbatim (GV=8, 320 thr).

#define NN    6000
#define DEG   16
#define MM    17
#define NTPL  16
#define MT    10
#define NF    128
#define NITER 10
#define KPB   16
#define NPB   3
#define BS    1024
#define RS    12            // padded T row stride (floats)
#define LOG2E 1.44269504088896340736f

template<int C>
__device__ __forceinline__ float ror_add(float v) {
    int s = __builtin_amdgcn_update_dpp(0, __float_as_int(v), C, 0xf, 0xf, true);
    return v + __int_as_float(s);
}

__device__ __forceinline__ float fexp2(float x) { return __builtin_amdgcn_exp2f(x); }
__device__ __forceinline__ float frcp(float x)  { return __builtin_amdgcn_rcpf(x); }

// ---------------- gcost (round-5 verbatim): G[v,kt] = mcoefl*(||F2||^2 - 2 x.F2)
#define GV 8
__global__ __launch_bounds__(320) void gcost_kernel(
    const float* __restrict__ x, const float* __restrict__ F2g,
    const float* __restrict__ alpha0, float* __restrict__ G)
{
    const int tx  = threadIdx.x;          // 0..39 : kt quad
    const int vs  = threadIdx.y;          // 0..7  : node in block
    const int tid = vs * 40 + tx;
    const int v0  = blockIdx.x * GV;

    __shared__ __align__(16) float s_x[GV][NF];        // 4 KB
    __shared__ __align__(16) float s_f2t[16][164];     // 10.5 KB

    {
        const float4* xg  = reinterpret_cast<const float4*>(x);
        float4*       sx4 = reinterpret_cast<float4*>(&s_x[0][0]);
        for (int i = tid; i < GV * 32; i += 320) {
            int row = i >> 5, c = i & 31;
            sx4[i] = xg[(size_t)(v0 + row) * 32 + c];
        }
    }

    float4 acc = make_float4(0.f, 0.f, 0.f, 0.f);
    float4 sq  = make_float4(0.f, 0.f, 0.f, 0.f);

    for (int fc = 0; fc < 8; fc++) {
        __syncthreads();
        for (int i = tid; i < 160 * 16; i += 320) {
            int kt = i >> 4, j = i & 15;
            s_f2t[j][kt] = F2g[(size_t)kt * NF + fc * 16 + j];
        }
        __syncthreads();

        const float4* sxr = reinterpret_cast<const float4*>(&s_x[vs][0]);
        #pragma unroll
        for (int u = 0; u < 4; u++) {
            float4 xa = sxr[fc * 4 + u];
            #pragma unroll
            for (int jj = 0; jj < 4; jj++) {
                float xs = (&xa.x)[jj];
                const float4* br = reinterpret_cast<const float4*>(&s_f2t[u * 4 + jj][0]);
                float4 b = br[tx];
                acc.x = fmaf(xs, b.x, acc.x); acc.y = fmaf(xs, b.y, acc.y);
                acc.z = fmaf(xs, b.z, acc.z); acc.w = fmaf(xs, b.w, acc.w);
                sq.x  = fmaf(b.x, b.x, sq.x); sq.y  = fmaf(b.y, b.y, sq.y);
                sq.z  = fmaf(b.z, b.z, sq.z); sq.w  = fmaf(b.w, b.w, sq.w);
            }
        }
    }

    const float alpha  = 1.f / (1.f + __expf(-alpha0[0]));
    const float mcoefl = (1.f - alpha) * 10.f * LOG2E;
    float4 g;
    g.x = mcoefl * (sq.x - 2.f * acc.x);
    g.y = mcoefl * (sq.y - 2.f * acc.y);
    g.z = mcoefl * (sq.z - 2.f * acc.z);
    g.w = mcoefl * (sq.w - 2.f * acc.w);
    float4* Gp = reinterpret_cast<float4*>(G + (size_t)(v0 + vs) * (NTPL * MT));
    Gp[tx] = g;
}

// ---------------- main kernel
__global__ __launch_bounds__(BS, 4) void srfgw_kernel(
    const float* __restrict__ x,
    const int*   __restrict__ dst,
    const float* __restrict__ C2g,
    const float* __restrict__ F2g,
    const float* __restrict__ alpha0,
    const float* __restrict__ G,
    int useG,
    float*       __restrict__ out)
{
    const int nb  = blockIdx.x * NPB;
    const int tid = threadIdx.x;

    __shared__ __align__(16) float s_T[KPB][NPB][MM][RS];     // 39168 B
    __shared__ __align__(16) float s_C2sq[KPB][MT][RS];       // 7680 B
    __shared__ __align__(16) float s_q[KPB][NPB][RS];         // 2304 B
    __shared__ __align__(16) float s_cc[KPB][NPB][RS];        // 2304 B
    __shared__ __align__(16) float s_A[KPB][RS];              // 768 B (iter-0 fold)
    __shared__ __align__(16) float s_B[KPB][RS];              // 768 B
    __shared__ __align__(16) int   s_adj[NPB * MM][DEG];      // 3264 B
    __shared__ int      s_nbr[NPB][MM];
    __shared__ unsigned s_mask[NPB][MM];

    const float aval  = alpha0[0];
    const float alpha = 1.f / (1.f + __expf(-aval));
    const float gcoef = 2.f * alpha * 10.f;
    const float tgl   = 2.f * gcoef * LOG2E;
    const float gl2   = gcoef * LOG2E;

    if (tid < NPB * MM) {
        int node = tid / MM, a0 = tid - node * MM;
        s_nbr[node][a0]  = (a0 == 0) ? (nb + node) : dst[(size_t)(nb + node) * DEG + a0 - 1];
        s_mask[node][a0] = 0u;
    }
    __syncthreads();

    if (tid < NPB * MM * DEG) {
        int r = tid >> 4, j = tid & 15;
        int node = r / MM, a0 = r - node * MM;
        s_adj[r][j] = dst[(size_t)s_nbr[node][a0] * DEG + j];
    }
    for (int i = tid; i < KPB * MT * MT; i += BS) {   // strided: 1600 > BS
        int kk = i / (MT * MT), rr = i - kk * (MT * MT);
        int rs = rr / MT, rt = rr - rs * MT;
        float v = C2g[i];
        s_C2sq[kk][rs][rt] = gl2 * v * v;
    }
    // iter-0 fold constants: A[k][s] = (tgl/170)*sum_t C2, B[k][s] = 0.1*gl2*sum_t C2^2
    if (tid < NTPL * MT) {
        int kk = tid / MT, s = tid - kk * MT;
        const float* cr = C2g + (size_t)kk * MT * MT + s * MT;
        float rs = 0.f, rq = 0.f;
        #pragma unroll
        for (int t = 0; t < MT; t++) { float c = cr[t]; rs += c; rq = fmaf(c, c, rq); }
        s_A[kk][s] = (tgl / 170.f) * rs;
        s_B[kk][s] = 0.1f * gl2 * rq;
    }
    __syncthreads();

    if (tid < NPB * MM * MM) {
        int node = tid / (MM * MM), rr = tid - node * (MM * MM);
        int pa = rr / MM, pb = rr - pa * MM;
        int vtgt = s_nbr[node][pb];
        const int* ar = s_adj[node * MM + pa];
        bool e = false;
        #pragma unroll
        for (int j = 0; j < DEG; j++) e = e | (ar[j] == vtgt);
        if (e) {
            atomicOr(&s_mask[node][pa], 1u << pb);
            atomicOr(&s_mask[node][pb], 1u << pa);
        }
    }
    __syncthreads();

    // ---- lane mapping: wave kw owns template kw; 3 groups/wave ----
    const int  kw    = tid >> 6;
    const int  ln    = tid & 63;
    const bool isR16 = (ln >= 48) && (ln < 51);
    const bool valid = (ln < 51);
    int g = isR16 ? (ln - 48) : (ln >> 4);
    if (g >= NPB) g = 0;
    const int a = isR16 ? 16 : (ln & 15);

    const int k_u = __builtin_amdgcn_readfirstlane(kw);
    const float* __restrict__ c2p = C2g + (size_t)k_u * MT * MT;

    const int vv = s_nbr[g][a];

    float Mc[MT];
    if (useG) {
        const float2* gp = reinterpret_cast<const float2*>(G + (size_t)vv * (NTPL * MT) + k_u * MT);
        #pragma unroll
        for (int j = 0; j < 5; j++) {
            float2 w = gp[j];
            Mc[2 * j] = w.x; Mc[2 * j + 1] = w.y;
        }
    } else {
        float dot[MT], sq2[MT];
        #pragma unroll
        for (int t = 0; t < MT; t++) { dot[t] = 0.f; sq2[t] = 0.f; }
        const float4* xr = reinterpret_cast<const float4*>(x + (size_t)vv * NF);
        const float4* fr = reinterpret_cast<const float4*>(F2g + (size_t)k_u * MT * NF);
        for (int f = 0; f < NF / 4; f++) {
            float4 xa = xr[f];
            #pragma unroll
            for (int t = 0; t < MT; t++) {
                float4 b = fr[t * (NF / 4) + f];
                dot[t] += xa.x * b.x + xa.y * b.y + xa.z * b.z + xa.w * b.w;
                sq2[t] += b.x * b.x + b.y * b.y + b.z * b.z + b.w * b.w;
            }
        }
        const float mcoefl = (1.f - alpha) * 10.f * LOG2E;
        #pragma unroll
        for (int t = 0; t < MT; t++) Mc[t] = mcoefl * (sq2[t] - 2.f * dot[t]);
    }

    unsigned mask = valid ? s_mask[g][a] : 0u;
    const int  pcnt = __popc(mask);
    const bool cmpl = pcnt > 8;
    unsigned   lmask = cmpl ? (~mask & 0x1FFFFu) : mask;
    if (!valid) lmask = 0u;
    const float sgn = cmpl ? -1.f : 1.f;
    const float P   = 1.f / 17.f;

    // ---- iter-0 analytic fold: lt_1[s] = pcnt*A[s] - B[s] - Mc[s] ----
    float lt[MT];
    {
        const float pcf = (float)pcnt;
        const float2* Ap = reinterpret_cast<const float2*>(&s_A[kw][0]);
        const float2* Bp = reinterpret_cast<const float2*>(&s_B[kw][0]);
        #pragma unroll
        for (int j = 0; j < 5; j++) {
            float2 av = Ap[j], bv = Bp[j];
            lt[2 * j]     = fmaf(pcf, av.x, -bv.x - Mc[2 * j]);
            lt[2 * j + 1] = fmaf(pcf, av.y, -bv.y - Mc[2 * j + 1]);
        }
    }

    float4* Trow = reinterpret_cast<float4*>(&s_T[kw][g][a][0]);
    float q[MT];

    for (int it = 1; it <= NITER; it++) {
        // thread-local softmax (log2 domain, native v_exp_f32 + v_rcp_f32)
        float mx = lt[0];
        #pragma unroll
        for (int t = 1; t < MT; t++) mx = fmaxf(mx, lt[t]);
        float e[MT], ss = 0.f;
        #pragma unroll
        for (int t = 0; t < MT; t++) { e[t] = fexp2(lt[t] - mx); ss += e[t]; }
        float sc = P * frcp(ss);
        #pragma unroll
        for (int t = 0; t < MT; t++) e[t] *= sc;

        __builtin_amdgcn_wave_barrier();
        if (valid) {
            Trow[0] = make_float4(e[0], e[1], e[2], e[3]);
            Trow[1] = make_float4(e[4], e[5], e[6], e[7]);
            reinterpret_cast<float2*>(Trow)[4] = make_float2(e[8], e[9]);
        }
        __builtin_amdgcn_wave_barrier();

        // q via DPP rotate-reduce over 16-lane row (all 16 lanes get the sum)
        #pragma unroll
        for (int t = 0; t < MT; t++) {
            float s = e[t];
            s = ror_add<0x121>(s);
            s = ror_add<0x122>(s);
            s = ror_add<0x124>(s);
            s = ror_add<0x128>(s);
            q[t] = s;
        }
        if (valid && a < 16) {   // add row 16 from LDS
            const float4* r16 = reinterpret_cast<const float4*>(&s_T[kw][g][16][0]);
            float4 ra = r16[0], rb = r16[1];
            float2 rc = reinterpret_cast<const float2*>(r16)[4];
            q[0] += ra.x; q[1] += ra.y; q[2] += ra.z; q[3] += ra.w;
            q[4] += rb.x; q[5] += rb.y; q[6] += rb.z; q[7] += rb.w;
            q[8] += rc.x; q[9] += rc.y;
        }
        if (valid && a == 0) {   // publish q (row-16 lanes + final output)
            float2* qp = reinterpret_cast<float2*>(&s_q[kw][g][0]);
            #pragma unroll
            for (int j = 0; j < 5; j++) qp[j] = make_float2(q[2 * j], q[2 * j + 1]);
        }
        __builtin_amdgcn_wave_barrier();
        if (isR16) {
            const float2* qp = reinterpret_cast<const float2*>(&s_q[kw][g][0]);
            #pragma unroll
            for (int j = 0; j < 5; j++) {
                float2 w = qp[j];
                q[2 * j] = w.x; q[2 * j + 1] = w.y;
            }
        }
        if (it == NITER) break;

        // cooperative cc[s] (C2sq pre-scaled by gcoef*log2e)
        if (valid && a < MT) {
            const float4* cr = reinterpret_cast<const float4*>(&s_C2sq[kw][a][0]);
            float4 ca = cr[0], cb = cr[1];
            float2 c2 = reinterpret_cast<const float2*>(cr)[4];
            float cc = q[0] * ca.x + q[1] * ca.y + q[2] * ca.z + q[3] * ca.w
                     + q[4] * cb.x + q[5] * cb.y + q[6] * cb.z + q[7] * cb.w
                     + q[8] * c2.x + q[9] * c2.y;
            s_cc[kw][g][a] = cc;
        }
        __builtin_amdgcn_wave_barrier();
        float ccr[MT];
        {
            const float4* cp = reinterpret_cast<const float4*>(&s_cc[kw][g][0]);
            float4 ca = cp[0], cb = cp[1];
            float2 c2 = reinterpret_cast<const float2*>(cp)[4];
            ccr[0] = ca.x; ccr[1] = ca.y; ccr[2] = ca.z; ccr[3] = ca.w;
            ccr[4] = cb.x; ccr[5] = cb.y; ccr[6] = cb.z; ccr[7] = cb.w;
            ccr[8] = c2.x; ccr[9] = c2.y;
        }

        // Y1 via bitmask (complement trick)
        float y1[MT];
        #pragma unroll
        for (int t = 0; t < MT; t++) y1[t] = cmpl ? q[t] : 0.f;
        unsigned mm = lmask;
        while (mm) {
            int b = __ffs(mm) - 1;
            mm &= mm - 1;
            const float4* rb4 = reinterpret_cast<const float4*>(&s_T[kw][g][b][0]);
            float4 ra = rb4[0], rb = rb4[1];
            float2 rc = reinterpret_cast<const float2*>(rb4)[4];
            y1[0] += sgn * ra.x; y1[1] += sgn * ra.y; y1[2] += sgn * ra.z; y1[3] += sgn * ra.w;
            y1[4] += sgn * rb.x; y1[5] += sgn * rb.y; y1[6] += sgn * rb.z; y1[7] += sgn * rb.w;
            y1[8] += sgn * rc.x; y1[9] += sgn * rc.y;
        }

        // y2 matvec (wave-uniform scalar C2) + log2-domain update
        #pragma unroll
        for (int s = 0; s < MT; s++) {
            float y2 = 0.f;
            #pragma unroll
            for (int t = 0; t < MT; t++) y2 = fmaf(y1[t], c2p[s * MT + t], y2);
            lt[s] += tgl * y2 - ccr[s] - Mc[s];
        }
    }

    if (valid && a < MT)
        out[(size_t)(nb + g) * (NTPL * MT) + k_u * MT + a] = s_q[kw][g][a];
}

extern "C" void kernel_launch(void* const* d_in, const int* in_sizes, int n_in,
                              void* d_out, int out_size, void* d_ws, size_t ws_size,
                              hipStream_t stream) {
    const float* x      = (const float*)d_in[0];
    const int*   eidx   = (const int*)d_in[1];
    const float* tmpl   = (const float*)d_in[2];
    const float* tmplf  = (const float*)d_in[3];
    const float* alpha0 = (const float*)d_in[4];
    float*       outp   = (float*)d_out;

    const int* dst = eidx + NN * DEG;
    float* G = (float*)d_ws;
    const size_t gbytes = (size_t)NN * NTPL * MT * sizeof(float);
    int useG = (ws_size >= gbytes) ? 1 : 0;

    if (useG)
        gcost_kernel<<<dim3(NN / GV), dim3(40, GV), 0, stream>>>(x, tmplf, alpha0, G);

    srfgw_kernel<<<dim3(NN / NPB), dim3(BS), 0, stream>>>(
        x, dst, tmpl, tmplf, alpha0, G, useG, outp);
}